// Round 2
// baseline (316.678 us; speedup 1.0000x reference)
//
#include <hip/hip_runtime.h>
#include <math.h>

// Problem constants: B=8, L=1024, D_MODEL=512, H=8, DK=DV=64.

typedef __attribute__((ext_vector_type(4))) float f32x4;
typedef __attribute__((ext_vector_type(8))) __bf16 bf8;
typedef __attribute__((ext_vector_type(8))) unsigned short us8;
typedef __attribute__((ext_vector_type(4))) unsigned short us4;

#define LOG2E 1.44269504088896f

static __device__ __forceinline__ unsigned short f2bf(float f) {
  union { float f; unsigned u; } x; x.f = f;
  unsigned r = x.u + 0x7fffu + ((x.u >> 16) & 1u);   // RNE
  return (unsigned short)(r >> 16);
}

static __device__ __forceinline__ f32x4 mfma16(bf8 a, bf8 b, f32x4 c) {
  return __builtin_amdgcn_mfma_f32_16x16x32_bf16(a, b, c, 0, 0, 0);
}

// ---------------- posi(h, i-j) lookup table: [8][2048], idx = (i-j)+1023 ----
// Pre-multiplied by log2(e) so attention can use exp2 directly.
__global__ void posi_build(const float* __restrict__ p0, const float* __restrict__ p1,
                           const float* __restrict__ p2, const float* __restrict__ p3,
                           float* __restrict__ tab) {
  int idx = blockIdx.x * 256 + threadIdx.x;
  if (idx >= 8 * 2048) return;
  int h = idx >> 11, dd = idx & 2047;
  if (dd >= 2047) { tab[idx] = 0.f; return; }
  float d = (float)(dd - 1023);         // d = qi - kj
  float s = fabsf(d);
  float a1 = p1[h], a2 = p2[h];
  float sp1 = (a1 > 20.f) ? a1 : log1pf(expf(a1));
  float sp2 = (a2 > 20.f) ? a2 : log1pf(expf(a2));
  float asyn = (d < 0.f) ? 1.f : 0.f;   // qi < kj
  tab[idx] = p0[h] * (expf(-sp1 * s) + expf(-sp2 * s) + p3[h] * asyn) * LOG2E;
}

// ---------------- GEMM: C[m,o] = A[m,:] . W[o,:] (+bias, epilogue) ----------
// M=8192, N=512, K=512. Tile 128x128x32, 4 waves, 16x16x32 bf16 MFMA.
// EPI=0: out bf16 to [b][h][l][d] (projections), scaled.
// EPI=1: out fp32 = acc + bias + resid (fc pre-LN).
template <int EPI, bool ABF>
__global__ __launch_bounds__(256) void gemm512(
    const void* __restrict__ Ap, const float* __restrict__ W,
    const float* __restrict__ bias, unsigned short* __restrict__ outb,
    float scale, const float* __restrict__ resid, float* __restrict__ outf) {
  __shared__ __align__(16) unsigned short As[128 * 32];
  __shared__ __align__(16) unsigned short Bs[128 * 32];
  const int tid = threadIdx.x;
  const int lane = tid & 63, w = tid >> 6;
  const int lg = lane >> 4, ln = lane & 15;
  const int wr = w >> 1, wc = w & 1;
  const int bm = blockIdx.x, bn = blockIdx.y;

  f32x4 acc[4][4] = {};

  for (int kt = 0; kt < 16; ++kt) {
    const int k0 = kt * 32;
    f32x4 areg[4]; us8 areg16[2]; f32x4 breg[4];
    if constexpr (!ABF) {
      const float* A = (const float*)Ap;
#pragma unroll
      for (int i = 0; i < 4; ++i) {
        int e = i * 1024 + tid * 4;
        int r = e >> 5, c = e & 31;
        areg[i] = *(const f32x4*)(A + (size_t)(bm * 128 + r) * 512 + k0 + c);
      }
    } else {
      const unsigned short* A = (const unsigned short*)Ap;
#pragma unroll
      for (int i = 0; i < 2; ++i) {
        int ch = i * 256 + tid;
        int r = ch >> 2, c = (ch & 3) * 8;
        areg16[i] = *(const us8*)(A + (size_t)(bm * 128 + r) * 512 + k0 + c);
      }
    }
#pragma unroll
    for (int i = 0; i < 4; ++i) {
      int e = i * 1024 + tid * 4;
      int r = e >> 5, c = e & 31;
      breg[i] = *(const f32x4*)(W + (size_t)(bn * 128 + r) * 512 + k0 + c);
    }
    __syncthreads();
    if constexpr (!ABF) {
#pragma unroll
      for (int i = 0; i < 4; ++i) {
        int e = i * 1024 + tid * 4;
        int r = e >> 5, c = e & 31;
        us4 u; u[0] = f2bf(areg[i][0]); u[1] = f2bf(areg[i][1]);
        u[2] = f2bf(areg[i][2]); u[3] = f2bf(areg[i][3]);
        *(us4*)&As[r * 32 + c] = u;
      }
    } else {
#pragma unroll
      for (int i = 0; i < 2; ++i) {
        int ch = i * 256 + tid;
        int r = ch >> 2, c = (ch & 3) * 8;
        *(us8*)&As[r * 32 + c] = areg16[i];
      }
    }
#pragma unroll
    for (int i = 0; i < 4; ++i) {
      int e = i * 1024 + tid * 4;
      int r = e >> 5, c = e & 31;
      us4 u; u[0] = f2bf(breg[i][0]); u[1] = f2bf(breg[i][1]);
      u[2] = f2bf(breg[i][2]); u[3] = f2bf(breg[i][3]);
      *(us4*)&Bs[r * 32 + c] = u;
    }
    __syncthreads();
    bf8 af[4], bfm[4];
#pragma unroll
    for (int m = 0; m < 4; ++m)
      af[m] = *(const bf8*)&As[(wr * 64 + m * 16 + ln) * 32 + lg * 8];
#pragma unroll
    for (int n = 0; n < 4; ++n)
      bfm[n] = *(const bf8*)&Bs[(wc * 64 + n * 16 + ln) * 32 + lg * 8];
#pragma unroll
    for (int m = 0; m < 4; ++m)
#pragma unroll
      for (int n = 0; n < 4; ++n)
        acc[m][n] = mfma16(af[m], bfm[n], acc[m][n]);
  }

#pragma unroll
  for (int m = 0; m < 4; ++m) {
#pragma unroll
    for (int n = 0; n < 4; ++n) {
      const int col = bn * 128 + wc * 64 + n * 16 + ln;
      const int row0 = bm * 128 + wr * 64 + m * 16 + lg * 4;
      const float bcol = bias[col];
#pragma unroll
      for (int r = 0; r < 4; ++r) {
        const int rg = row0 + r;
        float val = acc[m][n][r];
        if constexpr (EPI == 0) {
          val = (val + bcol) * scale;
          const int bb = rg >> 10, lq = rg & 1023, hh = col >> 6, dd = col & 63;
          outb[((size_t)(bb * 8 + hh) * 1024 + lq) * 64 + dd] = f2bf(val);
        } else {
          val = val + bcol + resid[(size_t)rg * 512 + col];
          outf[(size_t)rg * 512 + col] = val;
        }
      }
    }
  }
}

// ---------------- V transpose: [bh][l][d] -> [bh][d][l] --------------------
__global__ __launch_bounds__(256) void transpose_v(const unsigned short* __restrict__ VH,
                                                   unsigned short* __restrict__ VT) {
  __shared__ __align__(16) unsigned short t[64][72];
  const int bh = blockIdx.y;
  const int l0 = blockIdx.x * 64;
  const unsigned short* src = VH + ((size_t)bh * 1024 + l0) * 64;
#pragma unroll
  for (int i = 0; i < 2; ++i) {
    int ch = i * 256 + threadIdx.x;
    int r = ch >> 3, c8 = ch & 7;
    *(us8*)&t[r][c8 * 8] = *(const us8*)(src + r * 64 + c8 * 8);
  }
  __syncthreads();
  unsigned short* dst = VT + (size_t)bh * 64 * 1024 + l0;
#pragma unroll
  for (int i = 0; i < 2; ++i) {
    int ch = i * 256 + threadIdx.x;
    int d = ch >> 3, l8 = ch & 7;
    us8 vv;
#pragma unroll
    for (int j = 0; j < 8; ++j) vv[j] = t[l8 * 8 + j][d];
    *(us8*)(dst + (size_t)d * 1024 + l8 * 8) = vv;
  }
}

// ---------------- fused attention (swapped QK^T, lane-local rows) ----------
// grid (16, 64): x = 64-row q-block, y = b*8+h. 4 waves, 16 q-rows per wave.
// S^T = mfma(K, Q): lane (lg,ln) reg r holds S[qi=ln][kj=lg*4+r] per 16-kj chunk.
// Pass A: l = sum exp2(s+posi) (no max; scores bounded).  Pass B: recompute,
// write normalized probs (dwordx4), PV via wave-private LDS relayout.
__global__ __launch_bounds__(256) void attn_fwd(
    const unsigned short* __restrict__ QH, const unsigned short* __restrict__ KH,
    const unsigned short* __restrict__ VT, const float* __restrict__ posi_tab,
    float* __restrict__ attn_out, unsigned short* __restrict__ Omat) {
  __shared__ float posi_s[2048];
  __shared__ __align__(16) unsigned short p_lds[4][16][80];   // stride 80: 160B rows, 16B-aligned reads

  const int tid = threadIdx.x;
  const int lane = tid & 63, w = tid >> 6;
  const int lg = lane >> 4, ln = lane & 15;
  const int bh = blockIdx.y, b = bh >> 3, h = bh & 7;

  for (int i = tid; i < 2048; i += 256) posi_s[i] = posi_tab[h * 2048 + i];
  __syncthreads();

  const int q0 = blockIdx.x * 64 + w * 16;
  const size_t base = (size_t)(b * 8 + h) * 1024 * 64;
  const unsigned short* Qb = QH + base;
  const unsigned short* Kb = KH + base;
  const unsigned short* Vb = VT + base;

  const int qi = q0 + ln;                 // this lane's q-row
  // Q b-fragments (Q pre-scaled by log2e/sqrt(dk) in projection epilogue)
  const bf8 bq0 = *(const bf8*)(Qb + (size_t)qi * 64 + lg * 8);
  const bf8 bq1 = *(const bf8*)(Qb + (size_t)qi * 64 + lg * 8 + 32);

  // ---- PASS A: row sum of exp2 ----
  float lacc = 0.f;
  for (int kt = 0; kt < 16; ++kt) {
    const int k0 = kt * 64;
#pragma unroll
    for (int n = 0; n < 4; ++n) {
      const unsigned short* kr = Kb + (size_t)(k0 + n * 16 + ln) * 64 + lg * 8;
      bf8 a0 = *(const bf8*)kr;
      bf8 a1 = *(const bf8*)(kr + 32);
      f32x4 s = {};
      s = mfma16(a0, bq0, s);
      s = mfma16(a1, bq1, s);
      const int pidx = qi - (k0 + n * 16 + lg * 4) + 1023;
#pragma unroll
      for (int r = 0; r < 4; ++r)
        lacc += exp2f(s[r] + posi_s[pidx - r]);
    }
  }
  lacc += __shfl_xor(lacc, 16, 64);
  lacc += __shfl_xor(lacc, 32, 64);
  const float rl = 1.f / lacc;

  // ---- PASS B: normalized probs out + PV ----
  f32x4 oacc[4] = {};
  float* ab = attn_out + (size_t)(h * 8 + b) * 1024 * 1024 + (size_t)qi * 1024;

  for (int kt = 0; kt < 16; ++kt) {
    const int k0 = kt * 64;
#pragma unroll
    for (int n = 0; n < 4; ++n) {
      const unsigned short* kr = Kb + (size_t)(k0 + n * 16 + ln) * 64 + lg * 8;
      bf8 a0 = *(const bf8*)kr;
      bf8 a1 = *(const bf8*)(kr + 32);
      f32x4 s = {};
      s = mfma16(a0, bq0, s);
      s = mfma16(a1, bq1, s);
      const int kcol = n * 16 + lg * 4;
      const int pidx = qi - (k0 + kcol) + 1023;
      f32x4 p;
#pragma unroll
      for (int r = 0; r < 4; ++r)
        p[r] = exp2f(s[r] + posi_s[pidx - r]) * rl;
      *(f32x4*)(ab + k0 + kcol) = p;                       // dwordx4 store
      us4 pb;
#pragma unroll
      for (int r = 0; r < 4; ++r) pb[r] = f2bf(p[r]);
      *(us4*)&p_lds[w][ln][kcol] = pb;                     // ds_write_b64
    }
    // A-fragments for PV: P[qi=ln][kj = win*32 + lg*8 + j]
    const bf8 pa0 = *(const bf8*)&p_lds[w][ln][lg * 8];
    const bf8 pa1 = *(const bf8*)&p_lds[w][ln][32 + lg * 8];
#pragma unroll
    for (int n = 0; n < 4; ++n) {
      const unsigned short* vr = Vb + (size_t)(n * 16 + ln) * 1024 + k0 + lg * 8;
      bf8 v0 = *(const bf8*)vr;
      bf8 v1 = *(const bf8*)(vr + 32);
      oacc[n] = mfma16(pa0, v0, oacc[n]);
      oacc[n] = mfma16(pa1, v1, oacc[n]);
    }
  }

#pragma unroll
  for (int n = 0; n < 4; ++n)
#pragma unroll
    for (int r = 0; r < 4; ++r)
      Omat[(size_t)(b * 1024 + q0 + lg * 4 + r) * 512 + h * 64 + n * 16 + ln] =
          f2bf(oacc[n][r]);
}

// ---------------- LayerNorm over 512, one wave per row ---------------------
__global__ __launch_bounds__(256) void ln_fused(const float* __restrict__ x,
                                                const float* __restrict__ g,
                                                const float* __restrict__ bb,
                                                float* __restrict__ out) {
  const int lane = threadIdx.x & 63, w = threadIdx.x >> 6;
  const size_t row = (size_t)blockIdx.x * 4 + w;
  const float* xr = x + row * 512;
  f32x4 v0 = *(const f32x4*)(xr + lane * 8);
  f32x4 v1 = *(const f32x4*)(xr + lane * 8 + 4);
  float s = v0[0] + v0[1] + v0[2] + v0[3] + v1[0] + v1[1] + v1[2] + v1[3];
  float sq = v0[0] * v0[0] + v0[1] * v0[1] + v0[2] * v0[2] + v0[3] * v0[3] +
             v1[0] * v1[0] + v1[1] * v1[1] + v1[2] * v1[2] + v1[3] * v1[3];
#pragma unroll
  for (int msk = 1; msk <= 32; msk <<= 1) {
    s += __shfl_xor(s, msk, 64);
    sq += __shfl_xor(sq, msk, 64);
  }
  const float mu = s * (1.f / 512.f);
  const float var = sq * (1.f / 512.f) - mu * mu;
  const float rs = rsqrtf(var + 1e-5f);
  f32x4 g0 = *(const f32x4*)(g + lane * 8), g1 = *(const f32x4*)(g + lane * 8 + 4);
  f32x4 b0 = *(const f32x4*)(bb + lane * 8), b1 = *(const f32x4*)(bb + lane * 8 + 4);
  f32x4 o0, o1;
#pragma unroll
  for (int j = 0; j < 4; ++j) {
    o0[j] = (v0[j] - mu) * rs * g0[j] + b0[j];
    o1[j] = (v1[j] - mu) * rs * g1[j] + b1[j];
  }
  *(f32x4*)(out + row * 512 + lane * 8) = o0;
  *(f32x4*)(out + row * 512 + lane * 8 + 4) = o1;
}

extern "C" void kernel_launch(void* const* d_in, const int* in_sizes, int n_in,
                              void* d_out, int out_size, void* d_ws, size_t ws_size,
                              hipStream_t stream) {
  const float* q   = (const float*)d_in[0];
  const float* k   = (const float*)d_in[1];
  const float* v   = (const float*)d_in[2];
  const float* wqW = (const float*)d_in[3];
  const float* wqb = (const float*)d_in[4];
  const float* wkW = (const float*)d_in[5];
  const float* wkb = (const float*)d_in[6];
  const float* wvW = (const float*)d_in[7];
  const float* wvb = (const float*)d_in[8];
  const float* fcW = (const float*)d_in[9];
  const float* fcb = (const float*)d_in[10];
  const float* lng = (const float*)d_in[11];
  const float* lnb = (const float*)d_in[12];
  const float* p0  = (const float*)d_in[13];
  const float* p1  = (const float*)d_in[14];
  const float* p2  = (const float*)d_in[15];
  const float* p3  = (const float*)d_in[16];

  char* ws = (char*)d_ws;
  unsigned short* QH   = (unsigned short*)(ws);              //  8 MiB  [b][h][l][64] bf16
  unsigned short* KH   = (unsigned short*)(ws + 8388608);    //  8 MiB
  unsigned short* VH   = (unsigned short*)(ws + 16777216);   //  8 MiB
  unsigned short* VT   = (unsigned short*)(ws + 25165824);   //  8 MiB  [b][h][64][l]
  unsigned short* Omat = (unsigned short*)(ws + 33554432);   //  8 MiB  [b*l][512] bf16
  float* posi          = (float*)(ws + 41943040);            // 64 KiB
  float* preln         = (float*)(ws + 42008576);            // 16 MiB  fp32

  float* out0 = (float*)d_out;
  float* attn = out0 + (size_t)8 * 1024 * 512;

  posi_build<<<64, 256, 0, stream>>>(p0, p1, p2, p3, posi);
  // Q projection pre-scaled by log2(e)/sqrt(64) so attn uses exp2 directly.
  gemm512<0, false><<<dim3(64, 4), 256, 0, stream>>>(q, wqW, wqb, QH, 0.125f * LOG2E, nullptr, nullptr);
  gemm512<0, false><<<dim3(64, 4), 256, 0, stream>>>(k, wkW, wkb, KH, 1.f, nullptr, nullptr);
  gemm512<0, false><<<dim3(64, 4), 256, 0, stream>>>(v, wvW, wvb, VH, 1.f, nullptr, nullptr);
  transpose_v<<<dim3(16, 64), 256, 0, stream>>>(VH, VT);
  attn_fwd<<<dim3(16, 64), 256, 0, stream>>>(QH, KH, VT, posi, attn, Omat);
  gemm512<1, true><<<dim3(64, 4), 256, 0, stream>>>(Omat, fcW, fcb, nullptr, 1.f, q, preln);
  ln_fused<<<2048, 256, 0, stream>>>(preln, lng, lnb, out0);
}

// Round 3
// 311.197 us; speedup vs baseline: 1.0176x; 1.0176x over previous
//
#include <hip/hip_runtime.h>
#include <math.h>

// Problem constants: B=8, L=1024, D_MODEL=512, H=8, DK=DV=64.

typedef __attribute__((ext_vector_type(4))) float f32x4;
typedef __attribute__((ext_vector_type(8))) __bf16 bf8;
typedef __attribute__((ext_vector_type(8))) unsigned short us8;
typedef __attribute__((ext_vector_type(4))) unsigned short us4;

#define LOG2E 1.44269504088896f

static __device__ __forceinline__ unsigned short f2bf(float f) {
  union { float f; unsigned u; } x; x.f = f;
  unsigned r = x.u + 0x7fffu + ((x.u >> 16) & 1u);   // RNE
  return (unsigned short)(r >> 16);
}

static __device__ __forceinline__ float bf2f(unsigned short u) {
  union { unsigned u; float f; } x; x.u = ((unsigned)u) << 16;
  return x.f;
}

static __device__ __forceinline__ f32x4 mfma16(bf8 a, bf8 b, f32x4 c) {
  return __builtin_amdgcn_mfma_f32_16x16x32_bf16(a, b, c, 0, 0, 0);
}

// ---------------- posi(h, i-j) lookup table: [8][2048], idx = (i-j)+1023 ----
// Pre-multiplied by log2(e) so attention can use exp2 directly.
__global__ void posi_build(const float* __restrict__ p0, const float* __restrict__ p1,
                           const float* __restrict__ p2, const float* __restrict__ p3,
                           float* __restrict__ tab) {
  int idx = blockIdx.x * 256 + threadIdx.x;
  if (idx >= 8 * 2048) return;
  int h = idx >> 11, dd = idx & 2047;
  if (dd >= 2047) { tab[idx] = 0.f; return; }
  float d = (float)(dd - 1023);         // d = qi - kj
  float s = fabsf(d);
  float a1 = p1[h], a2 = p2[h];
  float sp1 = (a1 > 20.f) ? a1 : log1pf(expf(a1));
  float sp2 = (a2 > 20.f) ? a2 : log1pf(expf(a2));
  float asyn = (d < 0.f) ? 1.f : 0.f;   // qi < kj
  tab[idx] = p0[h] * (expf(-sp1 * s) + expf(-sp2 * s) + p3[h] * asyn) * LOG2E;
}

// ---------------- GEMM: C[m,o] = A[m,:] . W[o,:] (+bias, epilogue) ----------
// M=8192, N=512, K=512. Tile 128x128x32, 4 waves, 16x16x32 bf16 MFMA.
// EPI=0: out bf16 to [b][h][l][d] (projections), scaled.
// EPI=1: out fp32 = acc + bias + resid (fc pre-LN).
template <int EPI, bool ABF>
__global__ __launch_bounds__(256) void gemm512(
    const void* __restrict__ Ap, const float* __restrict__ W,
    const float* __restrict__ bias, unsigned short* __restrict__ outb,
    float scale, const float* __restrict__ resid, float* __restrict__ outf) {
  __shared__ __align__(16) unsigned short As[128 * 32];
  __shared__ __align__(16) unsigned short Bs[128 * 32];
  const int tid = threadIdx.x;
  const int lane = tid & 63, w = tid >> 6;
  const int lg = lane >> 4, ln = lane & 15;
  const int wr = w >> 1, wc = w & 1;
  const int bm = blockIdx.x, bn = blockIdx.y;

  f32x4 acc[4][4] = {};

  for (int kt = 0; kt < 16; ++kt) {
    const int k0 = kt * 32;
    f32x4 areg[4]; us8 areg16[2]; f32x4 breg[4];
    if constexpr (!ABF) {
      const float* A = (const float*)Ap;
#pragma unroll
      for (int i = 0; i < 4; ++i) {
        int e = i * 1024 + tid * 4;
        int r = e >> 5, c = e & 31;
        areg[i] = *(const f32x4*)(A + (size_t)(bm * 128 + r) * 512 + k0 + c);
      }
    } else {
      const unsigned short* A = (const unsigned short*)Ap;
#pragma unroll
      for (int i = 0; i < 2; ++i) {
        int ch = i * 256 + tid;
        int r = ch >> 2, c = (ch & 3) * 8;
        areg16[i] = *(const us8*)(A + (size_t)(bm * 128 + r) * 512 + k0 + c);
      }
    }
#pragma unroll
    for (int i = 0; i < 4; ++i) {
      int e = i * 1024 + tid * 4;
      int r = e >> 5, c = e & 31;
      breg[i] = *(const f32x4*)(W + (size_t)(bn * 128 + r) * 512 + k0 + c);
    }
    __syncthreads();
    if constexpr (!ABF) {
#pragma unroll
      for (int i = 0; i < 4; ++i) {
        int e = i * 1024 + tid * 4;
        int r = e >> 5, c = e & 31;
        us4 u; u[0] = f2bf(areg[i][0]); u[1] = f2bf(areg[i][1]);
        u[2] = f2bf(areg[i][2]); u[3] = f2bf(areg[i][3]);
        *(us4*)&As[r * 32 + c] = u;
      }
    } else {
#pragma unroll
      for (int i = 0; i < 2; ++i) {
        int ch = i * 256 + tid;
        int r = ch >> 2, c = (ch & 3) * 8;
        *(us8*)&As[r * 32 + c] = areg16[i];
      }
    }
#pragma unroll
    for (int i = 0; i < 4; ++i) {
      int e = i * 1024 + tid * 4;
      int r = e >> 5, c = e & 31;
      us4 u; u[0] = f2bf(breg[i][0]); u[1] = f2bf(breg[i][1]);
      u[2] = f2bf(breg[i][2]); u[3] = f2bf(breg[i][3]);
      *(us4*)&Bs[r * 32 + c] = u;
    }
    __syncthreads();
    bf8 af[4], bfm[4];
#pragma unroll
    for (int m = 0; m < 4; ++m)
      af[m] = *(const bf8*)&As[(wr * 64 + m * 16 + ln) * 32 + lg * 8];
#pragma unroll
    for (int n = 0; n < 4; ++n)
      bfm[n] = *(const bf8*)&Bs[(wc * 64 + n * 16 + ln) * 32 + lg * 8];
#pragma unroll
    for (int m = 0; m < 4; ++m)
#pragma unroll
      for (int n = 0; n < 4; ++n)
        acc[m][n] = mfma16(af[m], bfm[n], acc[m][n]);
  }

#pragma unroll
  for (int m = 0; m < 4; ++m) {
#pragma unroll
    for (int n = 0; n < 4; ++n) {
      const int col = bn * 128 + wc * 64 + n * 16 + ln;
      const int row0 = bm * 128 + wr * 64 + m * 16 + lg * 4;
      const float bcol = bias[col];
#pragma unroll
      for (int r = 0; r < 4; ++r) {
        const int rg = row0 + r;
        float val = acc[m][n][r];
        if constexpr (EPI == 0) {
          val = (val + bcol) * scale;
          const int bb = rg >> 10, lq = rg & 1023, hh = col >> 6, dd = col & 63;
          outb[((size_t)(bb * 8 + hh) * 1024 + lq) * 64 + dd] = f2bf(val);
        } else {
          val = val + bcol + resid[(size_t)rg * 512 + col];
          outf[(size_t)rg * 512 + col] = val;
        }
      }
    }
  }
}

// ---------------- V transpose: [bh][l][d] -> [bh][d][l] --------------------
__global__ __launch_bounds__(256) void transpose_v(const unsigned short* __restrict__ VH,
                                                   unsigned short* __restrict__ VT) {
  __shared__ __align__(16) unsigned short t[64][72];
  const int bh = blockIdx.y;
  const int l0 = blockIdx.x * 64;
  const unsigned short* src = VH + ((size_t)bh * 1024 + l0) * 64;
#pragma unroll
  for (int i = 0; i < 2; ++i) {
    int ch = i * 256 + threadIdx.x;
    int r = ch >> 3, c8 = ch & 7;
    *(us8*)&t[r][c8 * 8] = *(const us8*)(src + r * 64 + c8 * 8);
  }
  __syncthreads();
  unsigned short* dst = VT + (size_t)bh * 64 * 1024 + l0;
#pragma unroll
  for (int i = 0; i < 2; ++i) {
    int ch = i * 256 + threadIdx.x;
    int d = ch >> 3, l8 = ch & 7;
    us8 vv;
#pragma unroll
    for (int j = 0; j < 8; ++j) vv[j] = t[l8 * 8 + j][d];
    *(us8*)(dst + (size_t)d * 1024 + l8 * 8) = vv;
  }
}

// ---------------- fused attention (swapped QK^T, lane-local rows) ----------
// 1D grid 1024: wgid = qblk*64 + bh  =>  all 16 qblk-WGs of one (b,h) land on
// XCD bh%8 (round-robin on wgid). Per-XCD read set = 8 slabs (~3MB) -> L2-fit.
// 4 waves, 16 q-rows/wave. S^T = mfma(K, Q): lane(lg,ln) reg r holds
// S[qi=ln][kj=lg*4+r] per 16-kj chunk. Pass A: lacc = sum exp2(s+posi).
// Pass B: recompute, normalized bf16 P -> p_lds; PV from p_lds; attn store
// gathered via p_lds (4x256B segments per instr).
__global__ __launch_bounds__(256) void attn_fwd(
    const unsigned short* __restrict__ QH, const unsigned short* __restrict__ KH,
    const unsigned short* __restrict__ VT, const float* __restrict__ posi_tab,
    float* __restrict__ attn_out, unsigned short* __restrict__ Omat) {
  __shared__ float posi_s[2048];
  __shared__ __align__(16) unsigned short p_lds[4][16][80];   // 160B rows, 16B-aligned

  const int tid = threadIdx.x;
  const int lane = tid & 63, w = tid >> 6;
  const int lg = lane >> 4, ln = lane & 15;
  const int wgid = blockIdx.x;
  const int bh = wgid & 63, qblk = wgid >> 6;     // XCD-local: xcd = bh & 7
  const int b = bh >> 3, h = bh & 7;

  for (int i = tid; i < 2048; i += 256) posi_s[i] = posi_tab[h * 2048 + i];
  __syncthreads();

  const int q0 = qblk * 64 + w * 16;
  const size_t base = (size_t)(b * 8 + h) * 1024 * 64;
  const unsigned short* Qb = QH + base;
  const unsigned short* Kb = KH + base;
  const unsigned short* Vb = VT + base;

  const int qi = q0 + ln;                 // this lane's q-row
  // Q b-fragments (Q pre-scaled by log2e/sqrt(dk) in projection epilogue)
  const bf8 bq0 = *(const bf8*)(Qb + (size_t)qi * 64 + lg * 8);
  const bf8 bq1 = *(const bf8*)(Qb + (size_t)qi * 64 + lg * 8 + 32);

  // ---- PASS A: row sum of exp2 ----
  float lacc = 0.f;
  for (int kt = 0; kt < 16; ++kt) {
    const int k0 = kt * 64;
#pragma unroll
    for (int n = 0; n < 4; ++n) {
      const unsigned short* kr = Kb + (size_t)(k0 + n * 16 + ln) * 64 + lg * 8;
      bf8 a0 = *(const bf8*)kr;
      bf8 a1 = *(const bf8*)(kr + 32);
      f32x4 s = {};
      s = mfma16(a0, bq0, s);
      s = mfma16(a1, bq1, s);
      const int pidx = qi - (k0 + n * 16 + lg * 4) + 1023;
#pragma unroll
      for (int r = 0; r < 4; ++r)
        lacc += exp2f(s[r] + posi_s[pidx - r]);
    }
  }
  lacc += __shfl_xor(lacc, 16, 64);
  lacc += __shfl_xor(lacc, 32, 64);
  const float rl = 1.f / lacc;

  // ---- PASS B: normalized probs (bf16) -> p_lds; PV; gathered attn store --
  f32x4 oacc[4] = {};
  float* abb = attn_out + (size_t)(h * 8 + b) * 1024 * 1024;

  for (int kt = 0; kt < 16; ++kt) {
    const int k0 = kt * 64;
#pragma unroll
    for (int n = 0; n < 4; ++n) {
      const unsigned short* kr = Kb + (size_t)(k0 + n * 16 + ln) * 64 + lg * 8;
      bf8 a0 = *(const bf8*)kr;
      bf8 a1 = *(const bf8*)(kr + 32);
      f32x4 s = {};
      s = mfma16(a0, bq0, s);
      s = mfma16(a1, bq1, s);
      const int kcol = n * 16 + lg * 4;
      const int pidx = qi - (k0 + kcol) + 1023;
      us4 pb;
#pragma unroll
      for (int r = 0; r < 4; ++r)
        pb[r] = f2bf(exp2f(s[r] + posi_s[pidx - r]) * rl);
      *(us4*)&p_lds[w][ln][kcol] = pb;                     // ds_write_b64
    }
    // A-fragments for PV: P[qi=ln][kj = win*32 + lg*8 + j]
    const bf8 pa0 = *(const bf8*)&p_lds[w][ln][lg * 8];
    const bf8 pa1 = *(const bf8*)&p_lds[w][ln][32 + lg * 8];
#pragma unroll
    for (int n = 0; n < 4; ++n) {
      const unsigned short* vr = Vb + (size_t)(n * 16 + ln) * 1024 + k0 + lg * 8;
      bf8 v0 = *(const bf8*)vr;
      bf8 v1 = *(const bf8*)(vr + 32);
      oacc[n] = mfma16(pa0, v0, oacc[n]);
      oacc[n] = mfma16(pa1, v1, oacc[n]);
    }
    // Gathered attn store: per instr 4 rows x 256B contiguous segments.
#pragma unroll
    for (int j = 0; j < 4; ++j) {
      const int r = j * 4 + lg;
      const int c4 = ln * 4;
      us4 pv = *(const us4*)&p_lds[w][r][c4];
      f32x4 o;
#pragma unroll
      for (int t = 0; t < 4; ++t) o[t] = bf2f(pv[t]);
      *(f32x4*)(abb + (size_t)(q0 + r) * 1024 + k0 + c4) = o;
    }
  }

#pragma unroll
  for (int n = 0; n < 4; ++n)
#pragma unroll
    for (int r = 0; r < 4; ++r)
      Omat[(size_t)(b * 1024 + q0 + lg * 4 + r) * 512 + h * 64 + n * 16 + ln] =
          f2bf(oacc[n][r]);
}

// ---------------- LayerNorm over 512, one wave per row ---------------------
__global__ __launch_bounds__(256) void ln_fused(const float* __restrict__ x,
                                                const float* __restrict__ g,
                                                const float* __restrict__ bb,
                                                float* __restrict__ out) {
  const int lane = threadIdx.x & 63, w = threadIdx.x >> 6;
  const size_t row = (size_t)blockIdx.x * 4 + w;
  const float* xr = x + row * 512;
  f32x4 v0 = *(const f32x4*)(xr + lane * 8);
  f32x4 v1 = *(const f32x4*)(xr + lane * 8 + 4);
  float s = v0[0] + v0[1] + v0[2] + v0[3] + v1[0] + v1[1] + v1[2] + v1[3];
  float sq = v0[0] * v0[0] + v0[1] * v0[1] + v0[2] * v0[2] + v0[3] * v0[3] +
             v1[0] * v1[0] + v1[1] * v1[1] + v1[2] * v1[2] + v1[3] * v1[3];
#pragma unroll
  for (int msk = 1; msk <= 32; msk <<= 1) {
    s += __shfl_xor(s, msk, 64);
    sq += __shfl_xor(sq, msk, 64);
  }
  const float mu = s * (1.f / 512.f);
  const float var = sq * (1.f / 512.f) - mu * mu;
  const float rs = rsqrtf(var + 1e-5f);
  f32x4 g0 = *(const f32x4*)(g + lane * 8), g1 = *(const f32x4*)(g + lane * 8 + 4);
  f32x4 b0 = *(const f32x4*)(bb + lane * 8), b1 = *(const f32x4*)(bb + lane * 8 + 4);
  f32x4 o0, o1;
#pragma unroll
  for (int j = 0; j < 4; ++j) {
    o0[j] = (v0[j] - mu) * rs * g0[j] + b0[j];
    o1[j] = (v1[j] - mu) * rs * g1[j] + b1[j];
  }
  *(f32x4*)(out + row * 512 + lane * 8) = o0;
  *(f32x4*)(out + row * 512 + lane * 8 + 4) = o1;
}

extern "C" void kernel_launch(void* const* d_in, const int* in_sizes, int n_in,
                              void* d_out, int out_size, void* d_ws, size_t ws_size,
                              hipStream_t stream) {
  const float* q   = (const float*)d_in[0];
  const float* k   = (const float*)d_in[1];
  const float* v   = (const float*)d_in[2];
  const float* wqW = (const float*)d_in[3];
  const float* wqb = (const float*)d_in[4];
  const float* wkW = (const float*)d_in[5];
  const float* wkb = (const float*)d_in[6];
  const float* wvW = (const float*)d_in[7];
  const float* wvb = (const float*)d_in[8];
  const float* fcW = (const float*)d_in[9];
  const float* fcb = (const float*)d_in[10];
  const float* lng = (const float*)d_in[11];
  const float* lnb = (const float*)d_in[12];
  const float* p0  = (const float*)d_in[13];
  const float* p1  = (const float*)d_in[14];
  const float* p2  = (const float*)d_in[15];
  const float* p3  = (const float*)d_in[16];

  char* ws = (char*)d_ws;
  unsigned short* QH   = (unsigned short*)(ws);              //  8 MiB  [b][h][l][64] bf16
  unsigned short* KH   = (unsigned short*)(ws + 8388608);    //  8 MiB
  unsigned short* VH   = (unsigned short*)(ws + 16777216);   //  8 MiB
  unsigned short* VT   = (unsigned short*)(ws + 25165824);   //  8 MiB  [b][h][64][l]
  unsigned short* Omat = (unsigned short*)(ws + 33554432);   //  8 MiB  [b*l][512] bf16
  float* posi          = (float*)(ws + 41943040);            // 64 KiB
  float* preln         = (float*)(ws + 42008576);            // 16 MiB  fp32

  float* out0 = (float*)d_out;
  float* attn = out0 + (size_t)8 * 1024 * 512;

  posi_build<<<64, 256, 0, stream>>>(p0, p1, p2, p3, posi);
  // Q projection pre-scaled by log2(e)/sqrt(64) so attn uses exp2 directly.
  gemm512<0, false><<<dim3(64, 4), 256, 0, stream>>>(q, wqW, wqb, QH, 0.125f * LOG2E, nullptr, nullptr);
  gemm512<0, false><<<dim3(64, 4), 256, 0, stream>>>(k, wkW, wkb, KH, 1.f, nullptr, nullptr);
  gemm512<0, false><<<dim3(64, 4), 256, 0, stream>>>(v, wvW, wvb, VH, 1.f, nullptr, nullptr);
  transpose_v<<<dim3(16, 64), 256, 0, stream>>>(VH, VT);
  attn_fwd<<<1024, 256, 0, stream>>>(QH, KH, VT, posi, attn, Omat);
  gemm512<1, true><<<dim3(64, 4), 256, 0, stream>>>(Omat, fcW, fcb, nullptr, 1.f, q, preln);
  ln_fused<<<2048, 256, 0, stream>>>(preln, lng, lnb, out0);
}